// Round 7
// baseline (246.376 us; speedup 1.0000x reference)
//
#include <hip/hip_runtime.h>

#define TAL 0.07f
constexpr int N = 8192;
constexpr int D = 1024;
constexpr int NB = 64;                     // N / BM
constexpr int NTILES = NB * (NB + 1) / 2;  // 2080 = 8 * 260 (exact XCD split)
constexpr int TPX = NTILES / 8;            // 260 tiles per XCD chunk

typedef __bf16 bf16x8 __attribute__((ext_vector_type(8)));
typedef float f32x4 __attribute__((ext_vector_type(4)));

#define AS1 __attribute__((address_space(1)))
#define AS3 __attribute__((address_space(3)))

#define WAIT_VM(n) asm volatile("s_waitcnt vmcnt(" #n ")" ::: "memory")
#define WAIT_LGKM0 asm volatile("s_waitcnt lgkmcnt(0)" ::: "memory")
#define SCHED_FENCE __builtin_amdgcn_sched_barrier(0)
#define SBAR __builtin_amdgcn_s_barrier()

static __device__ __forceinline__ ushort f2bf(float x) {
    union { float f; uint32_t u; } c; c.f = x;
    uint32_t u = c.u;
    uint32_t r = (u + 0x7FFFu + ((u >> 16) & 1u)) >> 16;   // RNE
    return (ushort)r;
}

// Kernel 1: fp32 -> bf16 convert + row scale + fused label histogram.
__global__ __launch_bounds__(256) void prep_kernel(const float* __restrict__ F,
                                                   const int* __restrict__ lab,
                                                   ushort* __restrict__ Fb,
                                                   float* __restrict__ ascale,
                                                   int* __restrict__ hist) {
    int row = blockIdx.x * 4 + (threadIdx.x >> 6);
    int lane = threadIdx.x & 63;
    const float4* src = (const float4*)(F + (size_t)row * D);
    ushort4* dst = (ushort4*)(Fb + (size_t)row * D);
    float local = 0.f;
    #pragma unroll
    for (int it = 0; it < 4; ++it) {
        float4 v = src[it * 64 + lane];
        ushort4 o;
        o.x = f2bf(v.x); o.y = f2bf(v.y); o.z = f2bf(v.z); o.w = f2bf(v.w);
        dst[it * 64 + lane] = o;
        local += v.x*v.x + v.y*v.y + v.z*v.z + v.w*v.w;
    }
    #pragma unroll
    for (int off = 32; off; off >>= 1) local += __shfl_xor(local, off);
    if (lane == 0) {
        ascale[row] = rsqrtf(TAL * local);
        atomicAdd(&hist[lab[row]], 1);
    }
}

// Kernel 2: symmetric-tiled bf16 MFMA Gram matrix.
// - lower-triangle tiles only (row sums of off-diagonal tiles supply the
//   mirrored column contributions; ex and pos are symmetric)
// - 3-deep LDS buffering, counted s_waitcnt vmcnt(8) (never 0 in loop),
//   raw s_barrier — loads stay in flight across barriers (T4)
// - XOR swizzle chunk^=((row>>1)&3) on 16B chunks: conflict-free ds_read_b128;
//   applied as linear global_load_lds dest + inverse-permuted global source
//   + same XOR on read address (rule #21)
#define BM 128
#define BN 128
#define BK 32
#define TILE (BM * BK)   // ushorts per LDS tile buffer (8 KB)
#define NSTEP (D / BK)   // 32

__global__ __launch_bounds__(256, 3) void gemm_kernel(const ushort* __restrict__ Fb,
                                                      const float* __restrict__ ascale,
                                                      const int* __restrict__ lab,
                                                      float* __restrict__ gSumE,
                                                      float* __restrict__ gSumP) {
    __shared__ ushort sA[3][TILE];
    __shared__ ushort sB[3][TILE];
    __shared__ float rScale[BM], cScale[BN];
    __shared__ int rLab[BM], cLab[BN];

    // XCD-chunked bijective remap (T1): each XCD gets a contiguous band.
    int kblk = blockIdx.x;
    int b = (kblk & 7) * TPX + (kblk >> 3);

    // triangular decode: b = bi*(bi+1)/2 + bj, bj <= bi
    int bi = (int)((sqrtf(8.f * (float)b + 1.f) - 1.f) * 0.5f);
    while ((bi + 1) * (bi + 2) / 2 <= b) ++bi;
    while (bi * (bi + 1) / 2 > b) --bi;
    int bj = b - bi * (bi + 1) / 2;
    bool offdiag = (bi != bj);

    int I0 = bi * BM, J0 = bj * BN;
    int t = threadIdx.x;
    int lane = t & 63, w = t >> 6;
    int wr = w >> 1, wc = w & 1;

    if (t < 128) { rScale[t] = ascale[I0 + t]; rLab[t] = lab[I0 + t]; }
    else { int u = t - 128; cScale[u] = ascale[J0 + u]; cLab[u] = lab[J0 + u]; }

    f32x4 acc[4][4];
    #pragma unroll
    for (int m = 0; m < 4; ++m)
        #pragma unroll
        for (int n = 0; n < 4; ++n)
            acc[m][n] = {0.f, 0.f, 0.f, 0.f};

    // Staging geometry: wave w, instr q in {0,1}: LDS bytes [(w*2+q)*1024, +1024)
    // = rows (w*2+q)*16 + l/4, physical 16B-chunk l&3. That chunk logically
    // holds col chunk (l&3) ^ ((l>>3)&3)  [swizzle chunk'=chunk^((row>>1)&3)].
    int r0 = (w * 2 + 0) * 16 + (lane >> 2);
    int r1 = (w * 2 + 1) * 16 + (lane >> 2);
    int ce = (((lane & 3) ^ ((lane >> 3) & 3))) * 8;   // swizzled source col (elems)
    const ushort* srcA0 = Fb + (size_t)(I0 + r0) * D + ce;
    const ushort* srcA1 = Fb + (size_t)(I0 + r1) * D + ce;
    const ushort* srcB0 = Fb + (size_t)(J0 + r0) * D + ce;
    const ushort* srcB1 = Fb + (size_t)(J0 + r1) * D + ce;
    ushort* sAf = &sA[0][0];
    ushort* sBf = &sB[0][0];
    int d0 = (w * 2 + 0) * 512;   // wave-uniform LDS dest (ushort units)
    int d1 = (w * 2 + 1) * 512;

#define STAGE(c, koff) do {                                                                              \
    __builtin_amdgcn_global_load_lds((const AS1 void*)(srcA0 + (koff)), (AS3 void*)(sAf + (c)*TILE + d0), 16, 0, 0); \
    __builtin_amdgcn_global_load_lds((const AS1 void*)(srcA1 + (koff)), (AS3 void*)(sAf + (c)*TILE + d1), 16, 0, 0); \
    __builtin_amdgcn_global_load_lds((const AS1 void*)(srcB0 + (koff)), (AS3 void*)(sBf + (c)*TILE + d0), 16, 0, 0); \
    __builtin_amdgcn_global_load_lds((const AS1 void*)(srcB1 + (koff)), (AS3 void*)(sBf + (c)*TILE + d1), 16, 0, 0); \
} while (0)

    int fr = lane & 15;                                   // fragment row within 16
    int cs = ((lane >> 4) ^ ((lane >> 1) & 3)) * 8;       // swizzled read chunk (elems);
                                                          // (row>>1)&3 == (lane>>1)&3 for row=..+fr

#define COMPUTE(cb, SECOND_BAR) do {                                                   \
    const ushort* a_ = sAf + (cb) * TILE;                                              \
    const ushort* b_ = sBf + (cb) * TILE;                                              \
    bf16x8 af[4], bfr[4];                                                              \
    _Pragma("unroll")                                                                  \
    for (int m = 0; m < 4; ++m)                                                        \
        af[m] = *(const bf16x8*)(a_ + (wr * 64 + m * 16 + fr) * BK + cs);              \
    _Pragma("unroll")                                                                  \
    for (int n = 0; n < 4; ++n)                                                        \
        bfr[n] = *(const bf16x8*)(b_ + (wc * 64 + n * 16 + fr) * BK + cs);             \
    WAIT_LGKM0; SCHED_FENCE;                                                           \
    if (SECOND_BAR) { SBAR; SCHED_FENCE; }                                             \
    _Pragma("unroll")                                                                  \
    for (int m = 0; m < 4; ++m)                                                        \
        _Pragma("unroll")                                                              \
        for (int n = 0; n < 4; ++n)                                                    \
            acc[m][n] = __builtin_amdgcn_mfma_f32_16x16x32_bf16(af[m], bfr[n], acc[m][n], 0, 0, 0); \
} while (0)

    // ITER t (main): stage tile t+2 -> buf (t+2)%3; wait own tile-t loads
    // (vmcnt(8): 12 in flight, 4 oldest = tile t); barrier => tile t visible;
    // read + lgkm-drain + barrier (=> safe for iter t+1 to overwrite buf t%3).
#define ITER(cb, sb, tt) do {                                                          \
    STAGE(sb, ((tt) + 2) * BK);                                                        \
    WAIT_VM(8); SCHED_FENCE; SBAR; SCHED_FENCE;                                        \
    COMPUTE(cb, 1);                                                                    \
} while (0)

    // prologue: tiles 0,1 -> bufs 0,1; __syncthreads drains everything once.
    STAGE(0, 0 * BK);
    STAGE(1, 1 * BK);
    __syncthreads();

    for (int s = 0; s < NSTEP - 2; s += 3) {
        ITER(0, 2, s);
        ITER(1, 0, s + 1);
        ITER(2, 1, s + 2);
    }
    // tail t = NSTEP-2 = 30 (buf 0): tile 31 still in flight -> vmcnt(4)
    WAIT_VM(4); SCHED_FENCE; SBAR; SCHED_FENCE;
    COMPUTE(0, 0);
    // tail t = NSTEP-1 = 31 (buf 1): drain
    WAIT_VM(0); SCHED_FENCE; SBAR; SCHED_FENCE;
    COMPUTE(1, 0);

    // Epilogue. C/D layout (m89-verified): col = lane&15, row = (lane>>4)*4 + reg.
    float rs[16]; int rl[16];
    int rbase = wr * 64 + (lane >> 4) * 4;
    #pragma unroll
    for (int m = 0; m < 4; ++m)
        #pragma unroll
        for (int r = 0; r < 4; ++r) {
            rs[m * 4 + r] = rScale[rbase + m * 16 + r];
            rl[m * 4 + r] = rLab[rbase + m * 16 + r];
        }

    const float CSH = 1.0f / TAL;
    float colE[4], colP[4], rowE[16], rowP[16];
    #pragma unroll
    for (int n = 0; n < 4; ++n) { colE[n] = 0.f; colP[n] = 0.f; }
    #pragma unroll
    for (int q = 0; q < 16; ++q) { rowE[q] = 0.f; rowP[q] = 0.f; }

    #pragma unroll
    for (int n = 0; n < 4; ++n) {
        int jl = wc * 64 + n * 16 + fr;
        float aj = cScale[jl];
        int lj = cLab[jl];
        #pragma unroll
        for (int m = 0; m < 4; ++m)
            #pragma unroll
            for (int r = 0; r < 4; ++r) {
                float ex = acc[m][n][r] * rs[m * 4 + r] * aj;
                float e = __expf(ex - CSH);
                float p = (rl[m * 4 + r] == lj) ? ex : 0.f;
                colE[n] += e; colP[n] += p;
                rowE[m * 4 + r] += e; rowP[m * 4 + r] += p;
            }
    }

    // column contributions (always): reduce across the 4 row-groups per wave
    #pragma unroll
    for (int n = 0; n < 4; ++n) {
        float se = colE[n], sp = colP[n];
        se += __shfl_xor(se, 16); se += __shfl_xor(se, 32);
        sp += __shfl_xor(sp, 16); sp += __shfl_xor(sp, 32);
        if (lane < 16) {
            int jl = wc * 64 + n * 16 + lane;
            atomicAdd(&gSumE[J0 + jl], se);
            atomicAdd(&gSumP[J0 + jl], sp);
        }
    }

    // row contributions (off-diagonal only): reduce across the 16 col-lanes
    if (offdiag) {
        #pragma unroll
        for (int q = 0; q < 16; ++q) {
            float se = rowE[q], sp = rowP[q];
            se += __shfl_xor(se, 1); se += __shfl_xor(se, 2);
            se += __shfl_xor(se, 4); se += __shfl_xor(se, 8);
            sp += __shfl_xor(sp, 1); sp += __shfl_xor(sp, 2);
            sp += __shfl_xor(sp, 4); sp += __shfl_xor(sp, 8);
            if ((lane & 15) == 0) {
                int row = rbase + (q >> 2) * 16 + (q & 3);
                atomicAdd(&gSumE[I0 + row], se);
                atomicAdd(&gSumP[I0 + row], sp);
            }
        }
    }
}

// Kernel 3: loss = (1/n) * sum_j [ 1/TAL + log(sumE[j]) - sumP[j]/n_pos[j] ]
__global__ __launch_bounds__(256) void finalize_kernel(const float* __restrict__ gSumE,
                                                       const float* __restrict__ gSumP,
                                                       const int* __restrict__ lab,
                                                       const int* __restrict__ hist,
                                                       float* __restrict__ out) {
    int t = threadIdx.x;
    const float CSH = 1.0f / TAL;
    float local = 0.f;
    for (int j = t; j < N; j += 256) {
        float np = (float)hist[lab[j]];
        local += CSH + logf(gSumE[j]) - gSumP[j] / np;
    }
    #pragma unroll
    for (int off = 32; off; off >>= 1) local += __shfl_xor(local, off);
    __shared__ float red[4];
    if ((t & 63) == 0) red[t >> 6] = local;
    __syncthreads();
    if (t == 0) out[0] = (red[0] + red[1] + red[2] + red[3]) / (float)N;
}

extern "C" void kernel_launch(void* const* d_in, const int* in_sizes, int n_in,
                              void* d_out, int out_size, void* d_ws, size_t ws_size,
                              hipStream_t stream) {
    const float* F = (const float*)d_in[0];
    const int* lab = (const int*)d_in[1];
    float* out = (float*)d_out;
    char* ws = (char*)d_ws;

    const size_t FB_BYTES = (size_t)N * D * 2;        // 16 MiB
    ushort* Fb    = (ushort*)ws;
    float* ascale = (float*)(ws + FB_BYTES);
    float* gSumE  = (float*)(ws + FB_BYTES + 32768);
    float* gSumP  = (float*)(ws + FB_BYTES + 65536);
    int*   hist   = (int*)  (ws + FB_BYTES + 98304);

    // zero accumulators (harness poisons ws with 0xAA before every launch)
    hipMemsetAsync(ws + FB_BYTES + 32768, 0, 65536 + 512, stream);

    prep_kernel<<<N / 4, 256, 0, stream>>>(F, lab, Fb, ascale, hist);
    gemm_kernel<<<NTILES, 256, 0, stream>>>(Fb, ascale, lab, gSumE, gSumP);
    finalize_kernel<<<1, 256, 0, stream>>>(gSumE, gSumP, lab, hist, out);
}

// Round 9
// 231.328 us; speedup vs baseline: 1.0651x; 1.0651x over previous
//
#include <hip/hip_runtime.h>

#define TAL 0.07f
constexpr int N = 8192;
constexpr int D = 1024;
constexpr int NB = 64;                     // N / BM
constexpr int NTILES = NB * (NB + 1) / 2;  // 2080 = 8 * 260 (exact XCD split)
constexpr int TPX = NTILES / 8;            // 260 tiles per XCD chunk

typedef __bf16 bf16x8 __attribute__((ext_vector_type(8)));
typedef float f32x4 __attribute__((ext_vector_type(4)));

#define AS1 __attribute__((address_space(1)))
#define AS3 __attribute__((address_space(3)))

#define WAIT_VM(n) asm volatile("s_waitcnt vmcnt(" #n ")" ::: "memory")
#define WAIT_LGKM0 asm volatile("s_waitcnt lgkmcnt(0)" ::: "memory")
#define SCHED_FENCE __builtin_amdgcn_sched_barrier(0)
#define SBAR __builtin_amdgcn_s_barrier()

static __device__ __forceinline__ ushort f2bf(float x) {
    union { float f; uint32_t u; } c; c.f = x;
    uint32_t u = c.u;
    uint32_t r = (u + 0x7FFFu + ((u >> 16) & 1u)) >> 16;   // RNE
    return (ushort)r;
}

// Kernel 1: fp32 -> bf16 convert + row scale + fused label histogram.
__global__ __launch_bounds__(256) void prep_kernel(const float* __restrict__ F,
                                                   const int* __restrict__ lab,
                                                   ushort* __restrict__ Fb,
                                                   float* __restrict__ ascale,
                                                   int* __restrict__ hist) {
    int row = blockIdx.x * 4 + (threadIdx.x >> 6);
    int lane = threadIdx.x & 63;
    const float4* src = (const float4*)(F + (size_t)row * D);
    ushort4* dst = (ushort4*)(Fb + (size_t)row * D);
    float local = 0.f;
    #pragma unroll
    for (int it = 0; it < 4; ++it) {
        float4 v = src[it * 64 + lane];
        ushort4 o;
        o.x = f2bf(v.x); o.y = f2bf(v.y); o.z = f2bf(v.z); o.w = f2bf(v.w);
        dst[it * 64 + lane] = o;
        local += v.x*v.x + v.y*v.y + v.z*v.z + v.w*v.w;
    }
    #pragma unroll
    for (int off = 32; off; off >>= 1) local += __shfl_xor(local, off);
    if (lane == 0) {
        ascale[row] = rsqrtf(TAL * local);
        atomicAdd(&hist[lab[row]], 1);
    }
}

// Kernel 2: symmetric-tiled bf16 MFMA Gram matrix.
// - lower-triangle tiles only; off-diagonal tiles also scatter row sums
//   (ex and pos are symmetric)
// - 3-deep LDS buffers, counted vmcnt (never 0 in loop), ONE barrier/step
// - register-fragment double-buffer: ds_read(t+1) issues before MFMA(t),
//   so lgkm latency hides under MFMA; MFMA path has no waits
// - XOR swizzle chunk^=((row>>1)&3): conflict-free ds_read_b128 (verified r7:
//   SQ_LDS_BANK_CONFLICT = 0), applied rule-21 both-sides
#define BM 128
#define BN 128
#define BK 32
#define TILE (BM * BK)   // ushorts per LDS tile buffer (8 KB)
#define NSTEP (D / BK)   // 32

__global__ __launch_bounds__(256, 3) void gemm_kernel(const ushort* __restrict__ Fb,
                                                      const float* __restrict__ ascale,
                                                      const int* __restrict__ lab,
                                                      float* __restrict__ gSumE,
                                                      float* __restrict__ gSumP) {
    __shared__ ushort sA[3][TILE];
    __shared__ ushort sB[3][TILE];
    __shared__ float rScale[BM], cScale[BN];
    __shared__ int rLab[BM], cLab[BN];

    // XCD-chunked bijective remap (T1): each XCD gets a contiguous band.
    int kblk = blockIdx.x;
    int b = (kblk & 7) * TPX + (kblk >> 3);

    // triangular decode: b = bi*(bi+1)/2 + bj, bj <= bi
    int bi = (int)((sqrtf(8.f * (float)b + 1.f) - 1.f) * 0.5f);
    while ((bi + 1) * (bi + 2) / 2 <= b) ++bi;
    while (bi * (bi + 1) / 2 > b) --bi;
    int bj = b - bi * (bi + 1) / 2;
    bool offdiag = (bi != bj);

    int I0 = bi * BM, J0 = bj * BN;
    int t = threadIdx.x;
    int lane = t & 63, w = t >> 6;
    int wr = w >> 1, wc = w & 1;

    if (t < 128) { rScale[t] = ascale[I0 + t]; rLab[t] = lab[I0 + t]; }
    else { int u = t - 128; cScale[u] = ascale[J0 + u]; cLab[u] = lab[J0 + u]; }

    f32x4 acc[4][4];
    #pragma unroll
    for (int m = 0; m < 4; ++m)
        #pragma unroll
        for (int n = 0; n < 4; ++n)
            acc[m][n] = {0.f, 0.f, 0.f, 0.f};

    // Staging geometry: wave w, instr q in {0,1}: LDS bytes [(w*2+q)*1024, +1024)
    // = rows (w*2+q)*16 + l/4, physical 16B chunk l&3, which logically holds
    // col chunk (l&3) ^ ((l>>3)&3)   [swizzle chunk' = chunk ^ ((row>>1)&3)].
    int r0 = (w * 2 + 0) * 16 + (lane >> 2);
    int r1 = (w * 2 + 1) * 16 + (lane >> 2);
    int ce = (((lane & 3) ^ ((lane >> 3) & 3))) * 8;   // swizzled source col (elems)
    const ushort* srcA0 = Fb + (size_t)(I0 + r0) * D + ce;
    const ushort* srcA1 = Fb + (size_t)(I0 + r1) * D + ce;
    const ushort* srcB0 = Fb + (size_t)(J0 + r0) * D + ce;
    const ushort* srcB1 = Fb + (size_t)(J0 + r1) * D + ce;
    ushort* sAf = &sA[0][0];
    ushort* sBf = &sB[0][0];
    int d0 = (w * 2 + 0) * 512;   // wave-uniform LDS dest (ushort units)
    int d1 = (w * 2 + 1) * 512;

#define STAGE(c, koff) do {                                                                              \
    __builtin_amdgcn_global_load_lds((const AS1 void*)(srcA0 + (koff)), (AS3 void*)(sAf + (c)*TILE + d0), 16, 0, 0); \
    __builtin_amdgcn_global_load_lds((const AS1 void*)(srcA1 + (koff)), (AS3 void*)(sAf + (c)*TILE + d1), 16, 0, 0); \
    __builtin_amdgcn_global_load_lds((const AS1 void*)(srcB0 + (koff)), (AS3 void*)(sBf + (c)*TILE + d0), 16, 0, 0); \
    __builtin_amdgcn_global_load_lds((const AS1 void*)(srcB1 + (koff)), (AS3 void*)(sBf + (c)*TILE + d1), 16, 0, 0); \
} while (0)

    int fr = lane & 15;                                   // fragment row within 16
    int cs = ((lane >> 4) ^ ((lane >> 1) & 3)) * 8;       // swizzled read chunk (elems)

#define DSREAD(AF, BF, cb) do {                                                        \
    const ushort* a_ = sAf + (cb) * TILE;                                              \
    const ushort* b_ = sBf + (cb) * TILE;                                              \
    _Pragma("unroll")                                                                  \
    for (int m = 0; m < 4; ++m)                                                        \
        AF[m] = *(const bf16x8*)(a_ + (wr * 64 + m * 16 + fr) * BK + cs);              \
    _Pragma("unroll")                                                                  \
    for (int n = 0; n < 4; ++n)                                                        \
        BF[n] = *(const bf16x8*)(b_ + (wc * 64 + n * 16 + fr) * BK + cs);              \
} while (0)

#define MFMA16(AF, BF) do {                                                            \
    _Pragma("unroll")                                                                  \
    for (int m = 0; m < 4; ++m)                                                        \
        _Pragma("unroll")                                                              \
        for (int n = 0; n < 4; ++n)                                                    \
            acc[m][n] = __builtin_amdgcn_mfma_f32_16x16x32_bf16(AF[m], BF[n], acc[m][n], 0, 0, 0); \
} while (0)

    // iter t: stage tile t+2; vmcnt(4) retires tile t+1's loads; SBAR makes
    // buf[(t+1)%3] visible to all; ds_read t+1 frags (into NXT regs) overlaps
    // MFMA on CUR regs (tile t, loaded last iter — no wait on its path);
    // trailing lgkm drain + next iter's SBAR gate the buf overwrite (2 iters away).
#define PITER(rb, sb, CA, CB, NA, NB_, tt) do {                                        \
    STAGE(sb, ((tt) + 2) * BK);                                                        \
    WAIT_VM(4); SCHED_FENCE; SBAR; SCHED_FENCE;                                        \
    DSREAD(NA, NB_, rb);                                                               \
    MFMA16(CA, CB);                                                                    \
    WAIT_LGKM0; SCHED_FENCE;                                                           \
} while (0)

    // prologue: tiles 0,1 -> bufs 0,1; full drain; tile-0 frags into set A.
    STAGE(0, 0 * BK);
    STAGE(1, 1 * BK);
    __syncthreads();
    bf16x8 afA[4], bfA[4], afB[4], bfB[4];
    DSREAD(afA, bfA, 0);
    WAIT_LGKM0; SCHED_FENCE;

    // 30 pipelined iters (t = 0..29), 6-unrolled (reg sets period 2, bufs period 3)
    for (int s = 0; s < NSTEP - 2; s += 6) {
        PITER(1, 2, afA, bfA, afB, bfB, s);
        PITER(2, 0, afB, bfB, afA, bfA, s + 1);
        PITER(0, 1, afA, bfA, afB, bfB, s + 2);
        PITER(1, 2, afB, bfB, afA, bfA, s + 3);
        PITER(2, 0, afA, bfA, afB, bfB, s + 4);
        PITER(0, 1, afB, bfB, afA, bfA, s + 5);
    }
    // tail: t=30 (frags in A; tile 31's 4 loads outstanding -> buf 1)
    WAIT_VM(0); SCHED_FENCE; SBAR; SCHED_FENCE;
    DSREAD(afB, bfB, 1);
    MFMA16(afA, bfA);
    MFMA16(afB, bfB);   // compiler inserts lgkm wait before first use

    // Epilogue. C/D layout (m89-verified): col = lane&15, row = (lane>>4)*4 + reg.
    float rs[16]; int rl[16];
    int rbase = wr * 64 + (lane >> 4) * 4;
    #pragma unroll
    for (int m = 0; m < 4; ++m)
        #pragma unroll
        for (int r = 0; r < 4; ++r) {
            rs[m * 4 + r] = rScale[rbase + m * 16 + r];
            rl[m * 4 + r] = rLab[rbase + m * 16 + r];
        }

    const float CSH = 1.0f / TAL;
    float colE[4], colP[4], rowE[16], rowP[16];
    #pragma unroll
    for (int n = 0; n < 4; ++n) { colE[n] = 0.f; colP[n] = 0.f; }
    #pragma unroll
    for (int q = 0; q < 16; ++q) { rowE[q] = 0.f; rowP[q] = 0.f; }

    #pragma unroll
    for (int n = 0; n < 4; ++n) {
        int jl = wc * 64 + n * 16 + fr;
        float aj = cScale[jl];
        int lj = cLab[jl];
        #pragma unroll
        for (int m = 0; m < 4; ++m)
            #pragma unroll
            for (int r = 0; r < 4; ++r) {
                float ex = acc[m][n][r] * rs[m * 4 + r] * aj;
                float e = __expf(ex - CSH);
                float p = (rl[m * 4 + r] == lj) ? ex : 0.f;
                colE[n] += e; colP[n] += p;
                rowE[m * 4 + r] += e; rowP[m * 4 + r] += p;
            }
    }

    // column contributions (always): reduce across the 4 row-groups per wave
    #pragma unroll
    for (int n = 0; n < 4; ++n) {
        float se = colE[n], sp = colP[n];
        se += __shfl_xor(se, 16); se += __shfl_xor(se, 32);
        sp += __shfl_xor(sp, 16); sp += __shfl_xor(sp, 32);
        if (lane < 16) {
            int jl = wc * 64 + n * 16 + lane;
            atomicAdd(&gSumE[J0 + jl], se);
            atomicAdd(&gSumP[J0 + jl], sp);
        }
    }

    // row contributions (off-diagonal only): reduce across the 16 col-lanes
    if (offdiag) {
        #pragma unroll
        for (int q = 0; q < 16; ++q) {
            float se = rowE[q], sp = rowP[q];
            se += __shfl_xor(se, 1); se += __shfl_xor(se, 2);
            se += __shfl_xor(se, 4); se += __shfl_xor(se, 8);
            sp += __shfl_xor(sp, 1); sp += __shfl_xor(sp, 2);
            sp += __shfl_xor(sp, 4); sp += __shfl_xor(sp, 8);
            if ((lane & 15) == 0) {
                int row = rbase + (q >> 2) * 16 + (q & 3);
                atomicAdd(&gSumE[I0 + row], se);
                atomicAdd(&gSumP[I0 + row], sp);
            }
        }
    }
}

// Kernel 3: loss contributions, 32 blocks, atomicAdd into zeroed d_out.
__global__ __launch_bounds__(256) void finalize_kernel(const float* __restrict__ gSumE,
                                                       const float* __restrict__ gSumP,
                                                       const int* __restrict__ lab,
                                                       const int* __restrict__ hist,
                                                       float* __restrict__ out) {
    int t = threadIdx.x;
    int j = blockIdx.x * 256 + t;
    const float CSH = 1.0f / TAL;
    float np = (float)hist[lab[j]];
    float local = CSH + logf(gSumE[j]) - gSumP[j] / np;
    #pragma unroll
    for (int off = 32; off; off >>= 1) local += __shfl_xor(local, off);
    __shared__ float red[4];
    if ((t & 63) == 0) red[t >> 6] = local;
    __syncthreads();
    if (t == 0) atomicAdd(out, (red[0] + red[1] + red[2] + red[3]) / (float)N);
}

extern "C" void kernel_launch(void* const* d_in, const int* in_sizes, int n_in,
                              void* d_out, int out_size, void* d_ws, size_t ws_size,
                              hipStream_t stream) {
    const float* F = (const float*)d_in[0];
    const int* lab = (const int*)d_in[1];
    float* out = (float*)d_out;
    char* ws = (char*)d_ws;

    const size_t FB_BYTES = (size_t)N * D * 2;        // 16 MiB
    ushort* Fb    = (ushort*)ws;
    float* ascale = (float*)(ws + FB_BYTES);
    float* gSumE  = (float*)(ws + FB_BYTES + 32768);
    float* gSumP  = (float*)(ws + FB_BYTES + 65536);
    int*   hist   = (int*)  (ws + FB_BYTES + 98304);

    // zero accumulators + output (harness poisons with 0xAA before every launch)
    hipMemsetAsync(ws + FB_BYTES + 32768, 0, 65536 + 512, stream);
    hipMemsetAsync(d_out, 0, sizeof(float), stream);

    prep_kernel<<<N / 4, 256, 0, stream>>>(F, lab, Fb, ascale, hist);
    gemm_kernel<<<NTILES, 256, 0, stream>>>(Fb, ascale, lab, gSumE, gSumP);
    finalize_kernel<<<N / 256, 256, 0, stream>>>(gSumE, gSumP, lab, hist, out);
}

// Round 10
// 212.479 us; speedup vs baseline: 1.1595x; 1.0887x over previous
//
#include <hip/hip_runtime.h>

#define TAL 0.07f
constexpr int N = 8192;
constexpr int D = 1024;
constexpr int NB = 64;                     // N / BM
constexpr int NTILES = NB * (NB + 1) / 2;  // 2080 = 8 * 260 (exact XCD split)
constexpr int TPX = NTILES / 8;            // 260 tiles per XCD chunk

typedef __bf16 bf16x8 __attribute__((ext_vector_type(8)));
typedef float f32x4 __attribute__((ext_vector_type(4)));

#define AS1 __attribute__((address_space(1)))
#define AS3 __attribute__((address_space(3)))

#define WAIT_VM(n) asm volatile("s_waitcnt vmcnt(" #n ")" ::: "memory")
#define SCHED_FENCE __builtin_amdgcn_sched_barrier(0)
#define SBAR __builtin_amdgcn_s_barrier()

static __device__ __forceinline__ ushort f2bf(float x) {
    union { float f; uint32_t u; } c; c.f = x;
    uint32_t u = c.u;
    uint32_t r = (u + 0x7FFFu + ((u >> 16) & 1u)) >> 16;   // RNE
    return (ushort)r;
}

// Kernel 1: fp32 -> bf16 convert + row scale; also zeroes gSumE/gSumP
// (16384 floats spread across the first 64 blocks) so no memset launch needed.
__global__ __launch_bounds__(256) void prep_kernel(const float* __restrict__ F,
                                                   ushort* __restrict__ Fb,
                                                   float* __restrict__ ascale,
                                                   float* __restrict__ gSumZ) {
    int gid = blockIdx.x * 256 + threadIdx.x;
    if (gid < 16384) gSumZ[gid] = 0.f;     // gSumE ++ gSumP (contiguous 64 KB)

    int row = blockIdx.x * 4 + (threadIdx.x >> 6);
    int lane = threadIdx.x & 63;
    const float4* src = (const float4*)(F + (size_t)row * D);
    ushort4* dst = (ushort4*)(Fb + (size_t)row * D);
    float local = 0.f;
    #pragma unroll
    for (int it = 0; it < 4; ++it) {
        float4 v = src[it * 64 + lane];
        ushort4 o;
        o.x = f2bf(v.x); o.y = f2bf(v.y); o.z = f2bf(v.z); o.w = f2bf(v.w);
        dst[it * 64 + lane] = o;
        local += v.x*v.x + v.y*v.y + v.z*v.z + v.w*v.w;
    }
    #pragma unroll
    for (int off = 32; off; off >>= 1) local += __shfl_xor(local, off);
    if (lane == 0) ascale[row] = rsqrtf(TAL * local);
}

// Kernel 2: symmetric-tiled bf16 MFMA Gram matrix.
// - lower-triangle tiles only; off-diagonal tiles also scatter row sums
//   (ex and pos are symmetric)
// - 3-deep LDS buffers, counted vmcnt (never 0 in loop), ONE barrier/step
// - register-fragment double-buffer; NO explicit trailing lgkm drain: the
//   compiler's partial lgkmcnt before the consuming MFMA (next iter) retires
//   the reads, and that wait precedes the next mid-barrier which precedes
//   the buffer overwrite -> race-free (derivation in round-10 notes)
// - T5 setprio(1) around the MFMA cluster
// - XOR swizzle chunk^=((row>>1)&3): conflict-free ds_read_b128 (verified:
//   SQ_LDS_BANK_CONFLICT = 0), applied rule-21 both-sides
#define BM 128
#define BN 128
#define BK 32
#define TILE (BM * BK)   // ushorts per LDS tile buffer (8 KB)
#define NSTEP (D / BK)   // 32

__global__ __launch_bounds__(256, 3) void gemm_kernel(const ushort* __restrict__ Fb,
                                                      const float* __restrict__ ascale,
                                                      const int* __restrict__ lab,
                                                      float* __restrict__ gSumE,
                                                      float* __restrict__ gSumP) {
    __shared__ ushort sA[3][TILE];
    __shared__ ushort sB[3][TILE];
    __shared__ float rScale[BM], cScale[BN];
    __shared__ int rLab[BM], cLab[BN];

    // XCD-chunked bijective remap (T1): each XCD gets a contiguous band.
    int kblk = blockIdx.x;
    int b = (kblk & 7) * TPX + (kblk >> 3);

    // triangular decode: b = bi*(bi+1)/2 + bj, bj <= bi
    int bi = (int)((sqrtf(8.f * (float)b + 1.f) - 1.f) * 0.5f);
    while ((bi + 1) * (bi + 2) / 2 <= b) ++bi;
    while (bi * (bi + 1) / 2 > b) --bi;
    int bj = b - bi * (bi + 1) / 2;
    bool offdiag = (bi != bj);

    int I0 = bi * BM, J0 = bj * BN;
    int t = threadIdx.x;
    int lane = t & 63, w = t >> 6;
    int wr = w >> 1, wc = w & 1;

    if (t < 128) { rScale[t] = ascale[I0 + t]; rLab[t] = lab[I0 + t]; }
    else { int u = t - 128; cScale[u] = ascale[J0 + u]; cLab[u] = lab[J0 + u]; }

    f32x4 acc[4][4];
    #pragma unroll
    for (int m = 0; m < 4; ++m)
        #pragma unroll
        for (int n = 0; n < 4; ++n)
            acc[m][n] = {0.f, 0.f, 0.f, 0.f};

    // Staging geometry: wave w, instr q in {0,1}: LDS bytes [(w*2+q)*1024, +1024)
    // = rows (w*2+q)*16 + l/4, physical 16B chunk l&3, which logically holds
    // col chunk (l&3) ^ ((l>>3)&3)   [swizzle chunk' = chunk ^ ((row>>1)&3)].
    int r0 = (w * 2 + 0) * 16 + (lane >> 2);
    int r1 = (w * 2 + 1) * 16 + (lane >> 2);
    int ce = (((lane & 3) ^ ((lane >> 3) & 3))) * 8;   // swizzled source col (elems)
    const ushort* srcA0 = Fb + (size_t)(I0 + r0) * D + ce;
    const ushort* srcA1 = Fb + (size_t)(I0 + r1) * D + ce;
    const ushort* srcB0 = Fb + (size_t)(J0 + r0) * D + ce;
    const ushort* srcB1 = Fb + (size_t)(J0 + r1) * D + ce;
    ushort* sAf = &sA[0][0];
    ushort* sBf = &sB[0][0];
    int d0 = (w * 2 + 0) * 512;   // wave-uniform LDS dest (ushort units)
    int d1 = (w * 2 + 1) * 512;

#define STAGE(c, koff) do {                                                                              \
    __builtin_amdgcn_global_load_lds((const AS1 void*)(srcA0 + (koff)), (AS3 void*)(sAf + (c)*TILE + d0), 16, 0, 0); \
    __builtin_amdgcn_global_load_lds((const AS1 void*)(srcA1 + (koff)), (AS3 void*)(sAf + (c)*TILE + d1), 16, 0, 0); \
    __builtin_amdgcn_global_load_lds((const AS1 void*)(srcB0 + (koff)), (AS3 void*)(sBf + (c)*TILE + d0), 16, 0, 0); \
    __builtin_amdgcn_global_load_lds((const AS1 void*)(srcB1 + (koff)), (AS3 void*)(sBf + (c)*TILE + d1), 16, 0, 0); \
} while (0)

    int fr = lane & 15;                                   // fragment row within 16
    int cs = ((lane >> 4) ^ ((lane >> 1) & 3)) * 8;       // swizzled read chunk (elems)

#define DSREAD(AF, BF, cb) do {                                                        \
    const ushort* a_ = sAf + (cb) * TILE;                                              \
    const ushort* b_ = sBf + (cb) * TILE;                                              \
    _Pragma("unroll")                                                                  \
    for (int m = 0; m < 4; ++m)                                                        \
        AF[m] = *(const bf16x8*)(a_ + (wr * 64 + m * 16 + fr) * BK + cs);              \
    _Pragma("unroll")                                                                  \
    for (int n = 0; n < 4; ++n)                                                        \
        BF[n] = *(const bf16x8*)(b_ + (wc * 64 + n * 16 + fr) * BK + cs);              \
} while (0)

#define MFMA16(AF, BF) do {                                                            \
    _Pragma("unroll")                                                                  \
    for (int m = 0; m < 4; ++m)                                                        \
        _Pragma("unroll")                                                              \
        for (int n = 0; n < 4; ++n)                                                    \
            acc[m][n] = __builtin_amdgcn_mfma_f32_16x16x32_bf16(AF[m], BF[n], acc[m][n], 0, 0, 0); \
} while (0)

    // iter t: stage tile t+2; vmcnt(4) retires tile t+1's loads; SBAR makes
    // buf[(t+1)%3] visible; ds_read t+1 frags overlaps MFMA(t) (prio-boosted).
    // No trailing lgkm drain: compiler's partial lgkm wait before next iter's
    // MFMA retires these reads; next mid-barrier orders them vs overwrite.
#define PITER(rb, sb, CA, CB, NA, NB_, tt) do {                                        \
    STAGE(sb, ((tt) + 2) * BK);                                                        \
    WAIT_VM(4); SCHED_FENCE; SBAR; SCHED_FENCE;                                        \
    DSREAD(NA, NB_, rb);                                                               \
    __builtin_amdgcn_s_setprio(1);                                                     \
    MFMA16(CA, CB);                                                                    \
    __builtin_amdgcn_s_setprio(0);                                                     \
} while (0)

    // prologue: tiles 0,1 -> bufs 0,1; full drain; tile-0 frags into set A.
    STAGE(0, 0 * BK);
    STAGE(1, 1 * BK);
    __syncthreads();
    bf16x8 afA[4], bfA[4], afB[4], bfB[4];
    DSREAD(afA, bfA, 0);

    // 30 pipelined iters (t = 0..29), 6-unrolled (reg sets period 2, bufs period 3)
    for (int s = 0; s < NSTEP - 2; s += 6) {
        PITER(1, 2, afA, bfA, afB, bfB, s);
        PITER(2, 0, afB, bfB, afA, bfA, s + 1);
        PITER(0, 1, afA, bfA, afB, bfB, s + 2);
        PITER(1, 2, afB, bfB, afA, bfA, s + 3);
        PITER(2, 0, afA, bfA, afB, bfB, s + 4);
        PITER(0, 1, afB, bfB, afA, bfA, s + 5);
    }
    // tail: t=30 (frags in A; tile 31's 4 loads outstanding -> buf 1)
    WAIT_VM(0); SCHED_FENCE; SBAR; SCHED_FENCE;
    DSREAD(afB, bfB, 1);
    MFMA16(afA, bfA);
    MFMA16(afB, bfB);   // compiler inserts lgkm wait before first use

    // Epilogue. C/D layout (m89-verified): col = lane&15, row = (lane>>4)*4 + reg.
    float rs[16]; int rl[16];
    int rbase = wr * 64 + (lane >> 4) * 4;
    #pragma unroll
    for (int m = 0; m < 4; ++m)
        #pragma unroll
        for (int r = 0; r < 4; ++r) {
            rs[m * 4 + r] = rScale[rbase + m * 16 + r];
            rl[m * 4 + r] = rLab[rbase + m * 16 + r];
        }

    const float CSH = 1.0f / TAL;
    float colE[4], colP[4], rowE[16], rowP[16];
    #pragma unroll
    for (int n = 0; n < 4; ++n) { colE[n] = 0.f; colP[n] = 0.f; }
    #pragma unroll
    for (int q = 0; q < 16; ++q) { rowE[q] = 0.f; rowP[q] = 0.f; }

    #pragma unroll
    for (int n = 0; n < 4; ++n) {
        int jl = wc * 64 + n * 16 + fr;
        float aj = cScale[jl];
        int lj = cLab[jl];
        #pragma unroll
        for (int m = 0; m < 4; ++m)
            #pragma unroll
            for (int r = 0; r < 4; ++r) {
                float ex = acc[m][n][r] * rs[m * 4 + r] * aj;
                float e = __expf(ex - CSH);
                float p = (rl[m * 4 + r] == lj) ? ex : 0.f;
                colE[n] += e; colP[n] += p;
                rowE[m * 4 + r] += e; rowP[m * 4 + r] += p;
            }
    }

    // column contributions (always): reduce across the 4 row-groups per wave
    #pragma unroll
    for (int n = 0; n < 4; ++n) {
        float se = colE[n], sp = colP[n];
        se += __shfl_xor(se, 16); se += __shfl_xor(se, 32);
        sp += __shfl_xor(sp, 16); sp += __shfl_xor(sp, 32);
        if (lane < 16) {
            int jl = wc * 64 + n * 16 + lane;
            atomicAdd(&gSumE[J0 + jl], se);
            atomicAdd(&gSumP[J0 + jl], sp);
        }
    }

    // row contributions (off-diagonal only): reduce across the 16 col-lanes
    if (offdiag) {
        #pragma unroll
        for (int q = 0; q < 16; ++q) {
            float se = rowE[q], sp = rowP[q];
            se += __shfl_xor(se, 1); se += __shfl_xor(se, 2);
            se += __shfl_xor(se, 4); se += __shfl_xor(se, 8);
            sp += __shfl_xor(sp, 1); sp += __shfl_xor(sp, 2);
            sp += __shfl_xor(sp, 4); sp += __shfl_xor(sp, 8);
            if ((lane & 15) == 0) {
                int row = rbase + (q >> 2) * 16 + (q & 3);
                atomicAdd(&gSumE[I0 + row], se);
                atomicAdd(&gSumP[I0 + row], sp);
            }
        }
    }
}

// Kernel 3: single block, 1024 threads. Builds the 80-bin label histogram in
// LDS, then loss = (1/n) * sum_j [ 1/TAL + log(sumE[j]) - sumP[j]/n_pos[j] ].
__global__ __launch_bounds__(1024) void finalize_kernel(const float* __restrict__ gSumE,
                                                        const float* __restrict__ gSumP,
                                                        const int* __restrict__ lab,
                                                        float* __restrict__ out) {
    __shared__ int h[80];
    __shared__ float red[16];
    int t = threadIdx.x;
    if (t < 80) h[t] = 0;
    __syncthreads();
    #pragma unroll
    for (int it = 0; it < N / 1024; ++it)
        atomicAdd(&h[lab[it * 1024 + t]], 1);
    __syncthreads();

    const float CSH = 1.0f / TAL;
    float local = 0.f;
    #pragma unroll
    for (int it = 0; it < N / 1024; ++it) {
        int j = it * 1024 + t;
        float np = (float)h[lab[j]];
        local += CSH + logf(gSumE[j]) - gSumP[j] / np;
    }
    #pragma unroll
    for (int off = 32; off; off >>= 1) local += __shfl_xor(local, off);
    if ((t & 63) == 0) red[t >> 6] = local;
    __syncthreads();
    if (t == 0) {
        float s = 0.f;
        #pragma unroll
        for (int i = 0; i < 16; ++i) s += red[i];
        out[0] = s / (float)N;
    }
}

extern "C" void kernel_launch(void* const* d_in, const int* in_sizes, int n_in,
                              void* d_out, int out_size, void* d_ws, size_t ws_size,
                              hipStream_t stream) {
    const float* F = (const float*)d_in[0];
    const int* lab = (const int*)d_in[1];
    float* out = (float*)d_out;
    char* ws = (char*)d_ws;

    const size_t FB_BYTES = (size_t)N * D * 2;        // 16 MiB
    ushort* Fb    = (ushort*)ws;
    float* ascale = (float*)(ws + FB_BYTES);
    float* gSumE  = (float*)(ws + FB_BYTES + 32768);  // 32 KB
    float* gSumP  = (float*)(ws + FB_BYTES + 65536);  // contiguous after gSumE

    prep_kernel<<<N / 4, 256, 0, stream>>>(F, Fb, ascale, gSumE);
    gemm_kernel<<<NTILES, 256, 0, stream>>>(Fb, ascale, lab, gSumE, gSumP);
    finalize_kernel<<<1, 1024, 0, stream>>>(gSumE, gSumP, lab, out);
}

// Round 11
// 202.303 us; speedup vs baseline: 1.2179x; 1.0503x over previous
//
#include <hip/hip_runtime.h>

#define TAL 0.07f
constexpr int N = 8192;
constexpr int D = 1024;
constexpr int NB = 64;                     // N / BM
constexpr int NTILES = NB * (NB + 1) / 2;  // 2080 = 8 * 260 (exact XCD split)
constexpr int TPX = NTILES / 8;            // 260 tiles per XCD chunk

typedef __bf16 bf16x8 __attribute__((ext_vector_type(8)));
typedef float f32x4 __attribute__((ext_vector_type(4)));

#define AS1 __attribute__((address_space(1)))
#define AS3 __attribute__((address_space(3)))

#define WAIT_VM(n) asm volatile("s_waitcnt vmcnt(" #n ")" ::: "memory")
#define WAIT_LGKM0 asm volatile("s_waitcnt lgkmcnt(0)" ::: "memory")
#define SCHED_FENCE __builtin_amdgcn_sched_barrier(0)
#define SBAR __builtin_amdgcn_s_barrier()

static __device__ __forceinline__ ushort f2bf(float x) {
    union { float f; uint32_t u; } c; c.f = x;
    uint32_t u = c.u;
    uint32_t r = (u + 0x7FFFu + ((u >> 16) & 1u)) >> 16;   // RNE
    return (ushort)r;
}

// Kernel 1: fp32 -> bf16 convert + row scale; also zeroes gSumE/gSumP
// (16384 floats spread across the first 64 blocks) so no memset launch needed.
__global__ __launch_bounds__(256) void prep_kernel(const float* __restrict__ F,
                                                   ushort* __restrict__ Fb,
                                                   float* __restrict__ ascale,
                                                   float* __restrict__ gSumZ) {
    int gid = blockIdx.x * 256 + threadIdx.x;
    if (gid < 16384) gSumZ[gid] = 0.f;     // gSumE ++ gSumP (contiguous 64 KB)

    int row = blockIdx.x * 4 + (threadIdx.x >> 6);
    int lane = threadIdx.x & 63;
    const float4* src = (const float4*)(F + (size_t)row * D);
    ushort4* dst = (ushort4*)(Fb + (size_t)row * D);
    float local = 0.f;
    #pragma unroll
    for (int it = 0; it < 4; ++it) {
        float4 v = src[it * 64 + lane];
        ushort4 o;
        o.x = f2bf(v.x); o.y = f2bf(v.y); o.z = f2bf(v.z); o.w = f2bf(v.w);
        dst[it * 64 + lane] = o;
        local += v.x*v.x + v.y*v.y + v.z*v.z + v.w*v.w;
    }
    #pragma unroll
    for (int off = 32; off; off >>= 1) local += __shfl_xor(local, off);
    if (lane == 0) ascale[row] = rsqrtf(TAL * local);
}

// Kernel 2: symmetric-tiled bf16 MFMA Gram matrix — EXACT round-9 schedule
// (twice-measured 130-135 us): 3-deep LDS buffers, counted vmcnt, one SBAR
// per step, register-fragment double-buffer with trailing lgkm drain, NO
// setprio (m190/r10: hurts lockstep structures).
// XOR swizzle chunk^=((row>>1)&3): SQ_LDS_BANK_CONFLICT = 0 (verified r7).
#define BM 128
#define BN 128
#define BK 32
#define TILE (BM * BK)   // ushorts per LDS tile buffer (8 KB)
#define NSTEP (D / BK)   // 32

__global__ __launch_bounds__(256, 3) void gemm_kernel(const ushort* __restrict__ Fb,
                                                      const float* __restrict__ ascale,
                                                      const int* __restrict__ lab,
                                                      float* __restrict__ gSumE,
                                                      float* __restrict__ gSumP) {
    __shared__ ushort sA[3][TILE];
    __shared__ ushort sB[3][TILE];
    __shared__ float rScale[BM], cScale[BN];
    __shared__ int rLab[BM], cLab[BN];

    // XCD-chunked bijective remap (T1): each XCD gets a contiguous band.
    int kblk = blockIdx.x;
    int b = (kblk & 7) * TPX + (kblk >> 3);

    // triangular decode: b = bi*(bi+1)/2 + bj, bj <= bi
    int bi = (int)((sqrtf(8.f * (float)b + 1.f) - 1.f) * 0.5f);
    while ((bi + 1) * (bi + 2) / 2 <= b) ++bi;
    while (bi * (bi + 1) / 2 > b) --bi;
    int bj = b - bi * (bi + 1) / 2;
    bool offdiag = (bi != bj);

    int I0 = bi * BM, J0 = bj * BN;
    int t = threadIdx.x;
    int lane = t & 63, w = t >> 6;
    int wr = w >> 1, wc = w & 1;

    if (t < 128) { rScale[t] = ascale[I0 + t]; rLab[t] = lab[I0 + t]; }
    else { int u = t - 128; cScale[u] = ascale[J0 + u]; cLab[u] = lab[J0 + u]; }

    f32x4 acc[4][4];
    #pragma unroll
    for (int m = 0; m < 4; ++m)
        #pragma unroll
        for (int n = 0; n < 4; ++n)
            acc[m][n] = {0.f, 0.f, 0.f, 0.f};

    // Staging geometry: wave w, instr q in {0,1}: LDS bytes [(w*2+q)*1024, +1024)
    // = rows (w*2+q)*16 + l/4, physical 16B chunk l&3, which logically holds
    // col chunk (l&3) ^ ((l>>3)&3)   [swizzle chunk' = chunk ^ ((row>>1)&3)].
    int r0 = (w * 2 + 0) * 16 + (lane >> 2);
    int r1 = (w * 2 + 1) * 16 + (lane >> 2);
    int ce = (((lane & 3) ^ ((lane >> 3) & 3))) * 8;   // swizzled source col (elems)
    const ushort* srcA0 = Fb + (size_t)(I0 + r0) * D + ce;
    const ushort* srcA1 = Fb + (size_t)(I0 + r1) * D + ce;
    const ushort* srcB0 = Fb + (size_t)(J0 + r0) * D + ce;
    const ushort* srcB1 = Fb + (size_t)(J0 + r1) * D + ce;
    ushort* sAf = &sA[0][0];
    ushort* sBf = &sB[0][0];
    int d0 = (w * 2 + 0) * 512;   // wave-uniform LDS dest (ushort units)
    int d1 = (w * 2 + 1) * 512;

#define STAGE(c, koff) do {                                                                              \
    __builtin_amdgcn_global_load_lds((const AS1 void*)(srcA0 + (koff)), (AS3 void*)(sAf + (c)*TILE + d0), 16, 0, 0); \
    __builtin_amdgcn_global_load_lds((const AS1 void*)(srcA1 + (koff)), (AS3 void*)(sAf + (c)*TILE + d1), 16, 0, 0); \
    __builtin_amdgcn_global_load_lds((const AS1 void*)(srcB0 + (koff)), (AS3 void*)(sBf + (c)*TILE + d0), 16, 0, 0); \
    __builtin_amdgcn_global_load_lds((const AS1 void*)(srcB1 + (koff)), (AS3 void*)(sBf + (c)*TILE + d1), 16, 0, 0); \
} while (0)

    int fr = lane & 15;                                   // fragment row within 16
    int cs = ((lane >> 4) ^ ((lane >> 1) & 3)) * 8;       // swizzled read chunk (elems)

#define DSREAD(AF, BF, cb) do {                                                        \
    const ushort* a_ = sAf + (cb) * TILE;                                              \
    const ushort* b_ = sBf + (cb) * TILE;                                              \
    _Pragma("unroll")                                                                  \
    for (int m = 0; m < 4; ++m)                                                        \
        AF[m] = *(const bf16x8*)(a_ + (wr * 64 + m * 16 + fr) * BK + cs);              \
    _Pragma("unroll")                                                                  \
    for (int n = 0; n < 4; ++n)                                                        \
        BF[n] = *(const bf16x8*)(b_ + (wc * 64 + n * 16 + fr) * BK + cs);              \
} while (0)

#define MFMA16(AF, BF) do {                                                            \
    _Pragma("unroll")                                                                  \
    for (int m = 0; m < 4; ++m)                                                        \
        _Pragma("unroll")                                                              \
        for (int n = 0; n < 4; ++n)                                                    \
            acc[m][n] = __builtin_amdgcn_mfma_f32_16x16x32_bf16(AF[m], BF[n], acc[m][n], 0, 0, 0); \
} while (0)

    // iter t: stage tile t+2; vmcnt(4) retires tile t+1's loads; SBAR makes
    // buf[(t+1)%3] visible to all; ds_read t+1 frags (into NXT regs) overlaps
    // MFMA on CUR regs (tile t, loaded last iter — no wait on its path);
    // trailing lgkm drain + next iter's SBAR gate the buf overwrite (2 iters away).
#define PITER(rb, sb, CA, CB, NA, NB_, tt) do {                                        \
    STAGE(sb, ((tt) + 2) * BK);                                                        \
    WAIT_VM(4); SCHED_FENCE; SBAR; SCHED_FENCE;                                        \
    DSREAD(NA, NB_, rb);                                                               \
    MFMA16(CA, CB);                                                                    \
    WAIT_LGKM0; SCHED_FENCE;                                                           \
} while (0)

    // prologue: tiles 0,1 -> bufs 0,1; full drain; tile-0 frags into set A.
    STAGE(0, 0 * BK);
    STAGE(1, 1 * BK);
    __syncthreads();
    bf16x8 afA[4], bfA[4], afB[4], bfB[4];
    DSREAD(afA, bfA, 0);
    WAIT_LGKM0; SCHED_FENCE;

    // 30 pipelined iters (t = 0..29), 6-unrolled (reg sets period 2, bufs period 3)
    for (int s = 0; s < NSTEP - 2; s += 6) {
        PITER(1, 2, afA, bfA, afB, bfB, s);
        PITER(2, 0, afB, bfB, afA, bfA, s + 1);
        PITER(0, 1, afA, bfA, afB, bfB, s + 2);
        PITER(1, 2, afB, bfB, afA, bfA, s + 3);
        PITER(2, 0, afA, bfA, afB, bfB, s + 4);
        PITER(0, 1, afB, bfB, afA, bfA, s + 5);
    }
    // tail: t=30 (frags in A; tile 31's 4 loads outstanding -> buf 1)
    WAIT_VM(0); SCHED_FENCE; SBAR; SCHED_FENCE;
    DSREAD(afB, bfB, 1);
    MFMA16(afA, bfA);
    MFMA16(afB, bfB);   // compiler inserts lgkm wait before first use

    // Epilogue. C/D layout (m89-verified): col = lane&15, row = (lane>>4)*4 + reg.
    float rs[16]; int rl[16];
    int rbase = wr * 64 + (lane >> 4) * 4;
    #pragma unroll
    for (int m = 0; m < 4; ++m)
        #pragma unroll
        for (int r = 0; r < 4; ++r) {
            rs[m * 4 + r] = rScale[rbase + m * 16 + r];
            rl[m * 4 + r] = rLab[rbase + m * 16 + r];
        }

    const float CSH = 1.0f / TAL;
    float colE[4], colP[4], rowE[16], rowP[16];
    #pragma unroll
    for (int n = 0; n < 4; ++n) { colE[n] = 0.f; colP[n] = 0.f; }
    #pragma unroll
    for (int q = 0; q < 16; ++q) { rowE[q] = 0.f; rowP[q] = 0.f; }

    #pragma unroll
    for (int n = 0; n < 4; ++n) {
        int jl = wc * 64 + n * 16 + fr;
        float aj = cScale[jl];
        int lj = cLab[jl];
        #pragma unroll
        for (int m = 0; m < 4; ++m)
            #pragma unroll
            for (int r = 0; r < 4; ++r) {
                float ex = acc[m][n][r] * rs[m * 4 + r] * aj;
                float e = __expf(ex - CSH);
                float p = (rl[m * 4 + r] == lj) ? ex : 0.f;
                colE[n] += e; colP[n] += p;
                rowE[m * 4 + r] += e; rowP[m * 4 + r] += p;
            }
    }

    // column contributions (always): reduce across the 4 row-groups per wave
    #pragma unroll
    for (int n = 0; n < 4; ++n) {
        float se = colE[n], sp = colP[n];
        se += __shfl_xor(se, 16); se += __shfl_xor(se, 32);
        sp += __shfl_xor(sp, 16); sp += __shfl_xor(sp, 32);
        if (lane < 16) {
            int jl = wc * 64 + n * 16 + lane;
            atomicAdd(&gSumE[J0 + jl], se);
            atomicAdd(&gSumP[J0 + jl], sp);
        }
    }

    // row contributions (off-diagonal only): reduce across the 16 col-lanes
    if (offdiag) {
        #pragma unroll
        for (int q = 0; q < 16; ++q) {
            float se = rowE[q], sp = rowP[q];
            se += __shfl_xor(se, 1); se += __shfl_xor(se, 2);
            se += __shfl_xor(se, 4); se += __shfl_xor(se, 8);
            sp += __shfl_xor(sp, 1); sp += __shfl_xor(sp, 2);
            sp += __shfl_xor(sp, 4); sp += __shfl_xor(sp, 8);
            if ((lane & 15) == 0) {
                int row = rbase + (q >> 2) * 16 + (q & 3);
                atomicAdd(&gSumE[I0 + row], se);
                atomicAdd(&gSumP[I0 + row], sp);
            }
        }
    }
}

// Kernel 3: single block, 1024 threads. Builds the 80-bin label histogram in
// LDS, then loss = (1/n) * sum_j [ 1/TAL + log(sumE[j]) - sumP[j]/n_pos[j] ].
__global__ __launch_bounds__(1024) void finalize_kernel(const float* __restrict__ gSumE,
                                                        const float* __restrict__ gSumP,
                                                        const int* __restrict__ lab,
                                                        float* __restrict__ out) {
    __shared__ int h[80];
    __shared__ float red[16];
    int t = threadIdx.x;
    if (t < 80) h[t] = 0;
    __syncthreads();
    #pragma unroll
    for (int it = 0; it < N / 1024; ++it)
        atomicAdd(&h[lab[it * 1024 + t]], 1);
    __syncthreads();

    const float CSH = 1.0f / TAL;
    float local = 0.f;
    #pragma unroll
    for (int it = 0; it < N / 1024; ++it) {
        int j = it * 1024 + t;
        float np = (float)h[lab[j]];
        local += CSH + logf(gSumE[j]) - gSumP[j] / np;
    }
    #pragma unroll
    for (int off = 32; off; off >>= 1) local += __shfl_xor(local, off);
    if ((t & 63) == 0) red[t >> 6] = local;
    __syncthreads();
    if (t == 0) {
        float s = 0.f;
        #pragma unroll
        for (int i = 0; i < 16; ++i) s += red[i];
        out[0] = s / (float)N;
    }
}

extern "C" void kernel_launch(void* const* d_in, const int* in_sizes, int n_in,
                              void* d_out, int out_size, void* d_ws, size_t ws_size,
                              hipStream_t stream) {
    const float* F = (const float*)d_in[0];
    const int* lab = (const int*)d_in[1];
    float* out = (float*)d_out;
    char* ws = (char*)d_ws;

    const size_t FB_BYTES = (size_t)N * D * 2;        // 16 MiB
    ushort* Fb    = (ushort*)ws;
    float* ascale = (float*)(ws + FB_BYTES);
    float* gSumE  = (float*)(ws + FB_BYTES + 32768);  // 32 KB
    float* gSumP  = (float*)(ws + FB_BYTES + 65536);  // contiguous after gSumE

    prep_kernel<<<N / 4, 256, 0, stream>>>(F, Fb, ascale, gSumE);
    gemm_kernel<<<NTILES, 256, 0, stream>>>(Fb, ascale, lab, gSumE, gSumP);
    finalize_kernel<<<1, 1024, 0, stream>>>(gSumE, gSumP, lab, out);
}